// Round 10
// baseline (120.226 us; speedup 1.0000x reference)
//
#include <hip/hip_runtime.h>
#include <hip/hip_fp16.h>
#include <stdint.h>

// Local-window (5x5) KDE histogram entropy, 256 bins, bandwidth 0.1.
// sigma'((x-b)/0.1) ~ exp(-10|x-b|): only bins b0=floor(v), b0+1 carry mass
// (truncation error ~2e-3 entropy vs 6.28e-2 threshold; validated R5-R9).
// Register-resident O(25^2) prefix-merge, telescoping T = sum_b M ln M via
// T += g(P+k)-g(P); H = ln S - T/S.  (Numerically identical to R9.)
//
// R10: occupancy attack. 1 px/lane = 3456 waves = 3.375 waves/SIMD -> every
// dependent chain exposed (R8 ILP restructure was neutral: the unrolled body
// is one basic block, compiler already had full freedom -> latency-bound on
// wave count). Split the merge across 2 waves per pixel set by OUTPUT index:
//   role A: T-terms i in [0,18)  (153 pairs, masses 0..17)
//   role B: T-terms i in [18,25) (147 pairs, masses 0..24 as pair sources)
// Same per-bin prefix order -> bit-identical numerics. 6912 waves = 6.75
// waves/SIMD wanted; per-wave ops ~halve. Combine via 1KB LDS + 1 barrier.
// Pair body now 5 ops via 64-bit funnel select:
//   t = (u32)(((u64)pj << 32) >> clamp(16d+32, 0, 63))
//   d=0 -> pj; d=1 -> pj>>16; d=-1 -> pj<<16; |d|>=2 -> 0
//   (d>=2 clamps to shift 63 -> bit63 = k1's fp16 sign = 0 for masses >= 0)

#define W 96
#define H 96
#define TPB 256
#define SPLIT 18

template<int NB, int I0>
__device__ __forceinline__ void role_compute(const float* __restrict__ base,
                                             int xcol, int y,
                                             float& Sout, float& Tout)
{
    // ---- loads (independent, batched) ----
    float va[NB];
    #pragma unroll
    for (int i = 0; i < NB; ++i) {
        const int dy = i / 5 - 2, dx = i % 5 - 2;
        const int yy = y + dy,    xx = xcol + dx;
        va[i] = base[min(max(yy, 0), H - 1) * W + min(max(xx, 0), W - 1)];
    }

    // ---- masses, packed fp16 (k1|k0) ----
    int b0a[NB]; uint32_t pk[NB];
    float S = 0.f;
    #pragma unroll
    for (int i = 0; i < NB; ++i) {
        const int dy = i / 5 - 2, dx = i % 5 - 2;
        const int yy = y + dy,    xx = xcol + dx;
        const bool ok = (yy >= 0) & (yy < H) & (xx >= 0) & (xx < W);
        const float v  = va[i];
        const int   b0 = (int)v;                    // v in [0,255) -> [0,254]
        const float f  = v - (float)b0;
        const float E  = __expf(-10.f * f);
        const float E2 = __expf(10.f * f - 10.f);
        const float r0 = __builtin_amdgcn_rcpf(1.f + E);
        const float r1 = __builtin_amdgcn_rcpf(1.f + E2);
        const float k0 = ok ? E  * r0 * r0 : 0.f;
        const float k1 = ok ? E2 * r1 * r1 : 0.f;
        const __half2 hk = __floats2half2_rn(k0, k1);
        if (i >= I0) {                              // S over my T-range only
            const float2 kc = __half22float2(hk);
            S += kc.x + kc.y;
        }
        b0a[i] = b0;
        pk[i]  = __builtin_bit_cast(uint32_t, hk);
    }

    // ---- prefix-merge + telescoping entropy terms for i in [I0, NB) ----
    float T0 = 0.f, T1 = 0.f;
    #pragma unroll
    for (int i = I0; i < NB; ++i) {
        const int b0i = b0a[i];
        uint32_t Ppk = 0u;
        #pragma unroll
        for (int j = 0; j < i; ++j) {
            const int d = b0i - b0a[j];
            int s = 16 * d + 32;
            s = s < 0 ? 0 : (s > 63 ? 63 : s);      // v_med3_i32
            const uint32_t t = (uint32_t)((((uint64_t)pk[j]) << 32) >> s);
            const __half2 sum = __hadd2(__builtin_bit_cast(__half2, Ppk),
                                        __builtin_bit_cast(__half2, t));
            Ppk = __builtin_bit_cast(uint32_t, sum);
        }
        const float2 P  = __half22float2(__builtin_bit_cast(__half2, Ppk));
        const float2 kc = __half22float2(__builtin_bit_cast(__half2, pk[i]));
        const float z0 = P.x + kc.x, z1 = P.y + kc.y;
        // g(z)=z ln(z+eps); g(0)=0; masked k=0 -> z==P -> term cancels
        const float t4 = z0 * __logf(z0 + 1e-10f) - P.x * __logf(P.x + 1e-10f)
                       + z1 * __logf(z1 + 1e-10f) - P.y * __logf(P.y + 1e-10f);
        if (i & 1) T1 += t4; else T0 += t4;
    }
    Sout = S;
    Tout = T0 + T1;
}

__global__ __launch_bounds__(TPB, 6) void entropy_kde_kernel(
    const float* __restrict__ x, float* __restrict__ out, int total)
{
    __shared__ float sS[128], sT[128];
    const int tid  = threadIdx.x;
    const int wv   = tid >> 6;          // wave 0..3
    const int g    = wv >> 1;           // pixel group 0/1 (64 px each)
    const int r    = wv & 1;            // role: 0 = A (i<18), 1 = B (i>=18)
    const int l    = tid & 63;
    const int slot = g * 64 + l;
    const int px   = blockIdx.x * 128 + slot;

    const int xcol = px % W;
    const int y    = (px / W) % H;
    const int img  = px / (W * H);
    const float* __restrict__ base = x + img * (H * W);

    float S, T;
    if (r == 0) role_compute<SPLIT, 0>(base, xcol, y, S, T);
    else        role_compute<25, SPLIT>(base, xcol, y, S, T);

    if (r == 1) { sS[slot] = S; sT[slot] = T; }
    __syncthreads();
    if (r == 0) {
        S += sS[slot];
        T += sT[slot];
        const float Sp = S + 1e-10f;
        if (px < total) out[px] = __logf(Sp) - T / Sp;
    }
}

extern "C" void kernel_launch(void* const* d_in, const int* in_sizes, int n_in,
                              void* d_out, int out_size, void* d_ws, size_t ws_size,
                              hipStream_t stream)
{
    const float* x = (const float*)d_in[0];
    float* out = (float*)d_out;
    const int total  = in_sizes[0];                    // 8*3*96*96 = 221184
    const int blocks = total / 128;                    // 1728 (exact)
    entropy_kde_kernel<<<blocks, TPB, 0, stream>>>(x, out, total);
}

// Round 11
// 80.732 us; speedup vs baseline: 1.4892x; 1.4892x over previous
//
#include <hip/hip_runtime.h>
#include <hip/hip_fp16.h>
#include <stdint.h>

// Local-window (5x5) KDE histogram entropy, 256 bins, bandwidth 0.1.
// sigma'((x-b)/0.1) ~ exp(-10|x-b|): only bins b0=floor(v), b0+1 carry mass
// (truncation error ~2e-3 entropy vs 6.28e-2 threshold; validated R5-R10).
// Register-resident O(25^2) prefix-merge, telescoping T = sum_b M ln M via
// T += g(P+k)-g(P); H = ln S - T/S.
//
// R11 = R10 minus the spill bomb. R10's __launch_bounds__(256,6) clamped
// VGPR to 40 -> all arrays spilled to scratch: FETCH 75MB + WRITE 150MB
// per dispatch at 41% HBM peak — the kernel was memory-bound on its own
// spills. Keep the 2-wave-per-pixel split (untested latency fix), drop the
// waves-per-EU clamp so the allocator takes ~90-110 VGPR with zero spills
// (~5 waves/SIMD resident vs 3.375 pre-split, and ~half the ops per wave).
//   role A: T-terms i in [0,18)  (153 pairs, masses 0..17)
//   role B: T-terms i in [18,25) (147 pairs, masses 0..24 as pair sources)
// Same per-bin prefix order -> numerics identical to R9/R10 (absmax 0.015625).
// Pair body: 64-bit funnel select
//   t = (u32)(((u64)pj << 32) >> med3(16d+32, 0, 63))
//   d=0 -> pj; d=1 -> pj>>16; d=-1 -> pj<<16; |d|>=2 -> 0 (fp16 sign bit = 0)

#define W 96
#define H 96
#define TPB 256
#define SPLIT 18

template<int NB, int I0>
__device__ __forceinline__ void role_compute(const float* __restrict__ base,
                                             int xcol, int y,
                                             float& Sout, float& Tout)
{
    // ---- masses, packed fp16 (k1|k0); load folded in (one basic block,
    // scheduler hoists loads as far as it likes; lower live ranges) ----
    int b0a[NB]; uint32_t pk[NB];
    float S = 0.f;
    #pragma unroll
    for (int i = 0; i < NB; ++i) {
        const int dy = i / 5 - 2, dx = i % 5 - 2;
        const int yy = y + dy,    xx = xcol + dx;
        const bool ok = (yy >= 0) & (yy < H) & (xx >= 0) & (xx < W);
        const float v  = base[min(max(yy, 0), H - 1) * W + min(max(xx, 0), W - 1)];
        const int   b0 = (int)v;                    // v in [0,255) -> [0,254]
        const float f  = v - (float)b0;
        const float E  = __expf(-10.f * f);
        const float E2 = __expf(10.f * f - 10.f);
        const float r0 = __builtin_amdgcn_rcpf(1.f + E);
        const float r1 = __builtin_amdgcn_rcpf(1.f + E2);
        const float k0 = ok ? E  * r0 * r0 : 0.f;
        const float k1 = ok ? E2 * r1 * r1 : 0.f;
        const __half2 hk = __floats2half2_rn(k0, k1);
        if (i >= I0) {                              // S over my T-range only
            const float2 kc = __half22float2(hk);
            S += kc.x + kc.y;
        }
        b0a[i] = b0;
        pk[i]  = __builtin_bit_cast(uint32_t, hk);
    }

    // ---- prefix-merge + telescoping entropy terms for i in [I0, NB) ----
    float T0 = 0.f, T1 = 0.f;
    #pragma unroll
    for (int i = I0; i < NB; ++i) {
        const int b0i = b0a[i];
        uint32_t Ppk = 0u;
        #pragma unroll
        for (int j = 0; j < i; ++j) {
            const int d = b0i - b0a[j];
            int s = 16 * d + 32;
            s = s < 0 ? 0 : (s > 63 ? 63 : s);      // v_med3_i32
            const uint32_t t = (uint32_t)((((uint64_t)pk[j]) << 32) >> s);
            const __half2 sum = __hadd2(__builtin_bit_cast(__half2, Ppk),
                                        __builtin_bit_cast(__half2, t));
            Ppk = __builtin_bit_cast(uint32_t, sum);
        }
        const float2 P  = __half22float2(__builtin_bit_cast(__half2, Ppk));
        const float2 kc = __half22float2(__builtin_bit_cast(__half2, pk[i]));
        const float z0 = P.x + kc.x, z1 = P.y + kc.y;
        // g(z)=z ln(z+eps); g(0)=0; masked k=0 -> z==P -> term cancels
        const float t4 = z0 * __logf(z0 + 1e-10f) - P.x * __logf(P.x + 1e-10f)
                       + z1 * __logf(z1 + 1e-10f) - P.y * __logf(P.y + 1e-10f);
        if (i & 1) T1 += t4; else T0 += t4;
    }
    Sout = S;
    Tout = T0 + T1;
}

__global__ __launch_bounds__(TPB) void entropy_kde_kernel(
    const float* __restrict__ x, float* __restrict__ out, int total)
{
    __shared__ float sS[128], sT[128];
    const int tid  = threadIdx.x;
    const int wv   = tid >> 6;          // wave 0..3
    const int g    = wv >> 1;           // pixel group 0/1 (64 px each)
    const int r    = wv & 1;            // role: 0 = A (i<18), 1 = B (i>=18)
    const int l    = tid & 63;
    const int slot = g * 64 + l;
    const int px   = blockIdx.x * 128 + slot;

    const int xcol = px % W;
    const int y    = (px / W) % H;
    const int img  = px / (W * H);
    const float* __restrict__ base = x + img * (H * W);

    float S, T;
    if (r == 0) role_compute<SPLIT, 0>(base, xcol, y, S, T);
    else        role_compute<25, SPLIT>(base, xcol, y, S, T);

    if (r == 1) { sS[slot] = S; sT[slot] = T; }
    __syncthreads();
    if (r == 0) {
        S += sS[slot];
        T += sT[slot];
        const float Sp = S + 1e-10f;
        if (px < total) out[px] = __logf(Sp) - T / Sp;
    }
}

extern "C" void kernel_launch(void* const* d_in, const int* in_sizes, int n_in,
                              void* d_out, int out_size, void* d_ws, size_t ws_size,
                              hipStream_t stream)
{
    const float* x = (const float*)d_in[0];
    float* out = (float*)d_out;
    const int total  = in_sizes[0];                    // 8*3*96*96 = 221184
    const int blocks = total / 128;                    // 1728 (exact)
    entropy_kde_kernel<<<blocks, TPB, 0, stream>>>(x, out, total);
}